// Round 2
// baseline (1898.833 us; speedup 1.0000x reference)
//
#include <hip/hip_runtime.h>
#include <math.h>

#define BB 256
#define CC 40
#define MAX_SWEEPS 16
#define TOL2 1e-12f   // relative off-diag^2 convergence threshold (tol=1e-6)
#define LSTR 36       // padded row stride (floats) for [32][36] LDS tiles

// ---- workspace layout (float offsets) ----
#define OFF_BM      0
#define OFF_Q       (CC*1024)
#define OFF_BMSQ    (2*CC*1024)
#define OFF_GT      (3*CC*1024)
#define OFF_BMNEW   (4*CC*1024)
#define OFF_R       (5*CC*1024)
#define OFF_MSQ     (6*CC*1024)
#define OFF_S       (7*CC*1024)          // C floats
#define OFF_SSQM    (7*CC*1024 + 64)     // C floats
#define OFF_XTPART  (7*CC*1024 + 128)    // 64*C*1024 floats
#define OFF_SSQPART (OFF_XTPART + 64*CC*1024)  // 64*C floats

// ---------------- device helpers ----------------

// One-sided (Hestenes) Jacobi, adaptive sweep count.
// Layout: lane = (h<<5)|j, column j (0..31), row-half h (rows h*16..h*16+15),
// g[16] = that half-column. XOR pairing m = 1..31 covers all pairs per sweep.
// Rotate only when gamma^2 > TOL2*alpha*beta (relative criterion) — this both
// stops noise-driven 45-degree flip-flops on degenerate pairs and provides
// the convergence predicate. Exit when a full sweep does no rotations.
__device__ __forceinline__ void jacobi(float g[16]) {
  for (int sw = 0; sw < MAX_SWEEPS; ++sw) {
    bool bad = false;
    for (int m = 1; m < 32; ++m) {
      float pc[16];
#pragma unroll
      for (int i = 0; i < 16; ++i) pc[i] = __shfl_xor(g[i], m);
      float aa = 0.f, gg = 0.f;
#pragma unroll
      for (int i = 0; i < 16; ++i) {
        aa = fmaf(g[i], g[i], aa);
        gg = fmaf(g[i], pc[i], gg);
      }
      float alpha = aa + __shfl_xor(aa, 32);   // own column norm^2 (full)
      float gamma = gg + __shfl_xor(gg, 32);   // dot(own, partner) (full)
      float beta  = __shfl_xor(alpha, m);      // partner norm^2
      bool rot = (gamma * gamma > TOL2 * alpha * beta);
      bad = bad || rot;
      float ag = fabsf(gamma);
      float zeta = (beta - alpha) / (2.f * copysignf(fmaxf(ag, 1e-30f), gamma));
      float t = copysignf(1.f, zeta) / (fabsf(zeta) + sqrtf(fmaf(zeta, zeta, 1.f)));
      t = rot ? t : 0.f;
      float c = rsqrtf(fmaf(t, t, 1.f));
      float s = t * c;
#pragma unroll
      for (int i = 0; i < 16; ++i) g[i] = fmaf(c, g[i], -(s * pc[i]));
    }
    if (!__any((int)bad)) break;
  }
}

__device__ __forceinline__ float colnorm2(const float g[16]) {
  float aa = 0.f;
#pragma unroll
  for (int i = 0; i < 16; ++i) aa = fmaf(g[i], g[i], aa);
  return aa + __shfl_xor(aa, 32);
}

// write G (converged columns) to per-wave LDS, column-major, stride LSTR
__device__ __forceinline__ void recon_write(float* Gc, const float g[16]) {
  int lane = threadIdx.x & 63, j = lane & 31, h = lane >> 5;
  float4* p = (float4*)(Gc + j * LSTR + h * 16);
#pragma unroll
  for (int q = 0; q < 4; ++q)
    p[q] = make_float4(g[4*q], g[4*q+1], g[4*q+2], g[4*q+3]);
}

// out[:,j] = sum_k coef[k] * Gc[:,k] * Gc[j,k]   (i.e. sum f(l_k) v_k v_k^T)
__device__ __forceinline__ void recon_read(const float* Gc, const float* coef, float out[16]) {
  int lane = threadIdx.x & 63, j = lane & 31, h = lane >> 5;
#pragma unroll
  for (int i = 0; i < 16; ++i) out[i] = 0.f;
#pragma unroll 4
  for (int k = 0; k < 32; ++k) {
    float w = coef[k] * Gc[k * LSTR + j];
    const float4* col = (const float4*)(Gc + k * LSTR + h * 16);
#pragma unroll
    for (int q = 0; q < 4; ++q) {
      float4 cv = col[q];
      out[4*q+0] = fmaf(w, cv.x, out[4*q+0]);
      out[4*q+1] = fmaf(w, cv.y, out[4*q+1]);
      out[4*q+2] = fmaf(w, cv.z, out[4*q+2]);
      out[4*q+3] = fmaf(w, cv.w, out[4*q+3]);
    }
  }
}

// out(own half) = M(row-major LDS, stride LSTR) * v(full 32-vector in regs)
__device__ __forceinline__ void matvec(const float* M, const float v[32], float out[16]) {
  int h = (threadIdx.x & 63) >> 5;
#pragma unroll
  for (int i = 0; i < 16; ++i) {
    const float4* row = (const float4*)(M + (h * 16 + i) * LSTR);
    float acc = 0.f;
#pragma unroll
    for (int q = 0; q < 8; ++q) {
      float4 r = row[q];
      acc = fmaf(r.x, v[4*q+0], acc);
      acc = fmaf(r.y, v[4*q+1], acc);
      acc = fmaf(r.z, v[4*q+2], acc);
      acc = fmaf(r.w, v[4*q+3], acc);
    }
    out[i] = acc;
  }
}

// assemble full 32-vector from the two half-columns (exchange across h)
__device__ __forceinline__ void fullvec(const float v[16], float vf[32]) {
  int h = (threadIdx.x & 63) >> 5;
  float o[16];
#pragma unroll
  for (int i = 0; i < 16; ++i) o[i] = __shfl_xor(v[i], 32);
#pragma unroll
  for (int k = 0; k < 16; ++k) {
    vf[k]      = h ? o[k] : v[k];
    vf[16 + k] = h ? v[k] : o[k];
  }
}

// load 32x32 row-major global matrix into column-register layout
__device__ __forceinline__ void load_cols_global(const float* base, float g[16]) {
  int lane = threadIdx.x & 63, j = lane & 31, h = lane >> 5;
#pragma unroll
  for (int i = 0; i < 16; ++i) g[i] = base[(h * 16 + i) * 32 + j];
}

// cooperative load of 1024 floats -> LDS [32][LSTR], 64-thread version
__device__ __forceinline__ void load_mat_lds64(const float* src, float* dst) {
  int t = threadIdx.x & 63;
  const float4* s = (const float4*)src;
#pragma unroll
  for (int q = 0; q < 4; ++q) {
    int idx = t + 64 * q, f = idx * 4;
    *(float4*)(dst + (f >> 5) * LSTR + (f & 31)) = s[idx];
  }
}

// ---------------- kernels ----------------

__global__ __launch_bounds__(256) void k1_mean(const float* __restrict__ X, float* __restrict__ ws) {
  int e = blockIdx.x * 256 + threadIdx.x;   // 0 .. C*1024
  int c = e >> 10, ei = e & 1023;
  const float* p = X + (size_t)c * 1024 + ei;
  float acc = 0.f;
  for (int b = 0; b < BB; ++b) acc += p[(size_t)b * (CC * 1024)];
  ws[OFF_BM + e] = acc * (1.f / BB);
}

__global__ __launch_bounds__(64) void k2_bm(float* __restrict__ ws) {
  __shared__ float Gc[32 * LSTR];
  __shared__ float coefA[32], coefB[32];
  int c = blockIdx.x;
  int lane = threadIdx.x & 63, j = lane & 31, h = lane >> 5;
  float g[16];
  load_cols_global(ws + OFF_BM + c * 1024, g);
  jacobi(g);
  float l2 = colnorm2(g), l = sqrtf(l2);
  float lh = fmaxf(l, 1e-6f);                 // eigenvalue clip (EIG_EPS)
  float inv_l2 = 1.f / fmaxf(l2, 1e-30f);
  float sq = sqrtf(lh);
  recon_write(Gc, g);
  if (h == 0) { coefA[j] = inv_l2 / sq; coefB[j] = sq * inv_l2; }
  __syncthreads();
  float o[16];
  recon_read(Gc, coefA, o);                   // Q = bm^{-1/2}
  float* Qp = ws + OFF_Q + c * 1024;
#pragma unroll
  for (int i = 0; i < 16; ++i) Qp[(h * 16 + i) * 32 + j] = o[i];
  recon_read(Gc, coefB, o);                   // bm^{1/2}
  float* Bp = ws + OFF_BMSQ + c * 1024;
#pragma unroll
  for (int i = 0; i < 16; ++i) Bp[(h * 16 + i) * 32 + j] = o[i];
}

__global__ __launch_bounds__(256) void k3_stage1(const float* __restrict__ X, float* __restrict__ ws) {
  __shared__ float Qlds[32 * LSTR];
  __shared__ float buf[4][32 * LSTR];   // per-wave: X tile, then reused as Gc
  __shared__ float coef[4][32];
  __shared__ float accum[32 * 33];
  __shared__ float ssqacc;
  int tid = threadIdx.x, wid = tid >> 6, lane = tid & 63, j = lane & 31, h = lane >> 5;
  int c = blockIdx.x % CC, bg = blockIdx.x / CC, b = bg * 4 + wid;

  for (int f = tid; f < 32 * 33; f += 256) accum[f] = 0.f;
  if (tid == 0) ssqacc = 0.f;
  { // Q -> LDS (block-wide)
    const float4* s = (const float4*)(ws + OFF_Q + c * 1024);
    int f = tid * 4;
    *(float4*)(Qlds + (f >> 5) * LSTR + (f & 31)) = s[tid];
  }
  { // X_b -> per-wave tile
    const float4* s = (const float4*)(X + ((size_t)(b * CC + c) << 10));
    float* d = buf[wid];
#pragma unroll
    for (int q = 0; q < 4; ++q) {
      int idx = lane + 64 * q, f = idx * 4;
      *(float4*)(d + (f >> 5) * LSTR + (f & 31)) = s[idx];
    }
  }
  __syncthreads();

  float qv[32];   // Q[:,j] == Q[j,:] (symmetric)
  { const float4* row = (const float4*)(Qlds + j * LSTR);
#pragma unroll
    for (int q = 0; q < 8; ++q) { float4 r = row[q];
      qv[4*q]=r.x; qv[4*q+1]=r.y; qv[4*q+2]=r.z; qv[4*q+3]=r.w; } }
  float z[16];  matvec(buf[wid], qv, z);   // z = X * q_j
  float zf[32]; fullvec(z, zf);
  float g[16];  matvec(Qlds, zf, g);       // g = Q * z = (Q X Q)[:,j]

  jacobi(g);
  float l2 = colnorm2(g), l = sqrtf(l2);
  float lw = logf(fmaxf(l, 1e-6f));
  float sq = lw * lw;                      // sum_j log^2 -> ||XT||_F^2
#pragma unroll
  for (int m = 1; m < 32; m <<= 1) sq += __shfl_xor(sq, m);
  if (lane == 0) atomicAdd(&ssqacc, sq);
  float cf = lw / fmaxf(l2, 1e-30f);

  __syncthreads();
  recon_write(buf[wid], g);                // reuse X tile as Gc
  if (h == 0) coef[wid][j] = cf;
  __syncthreads();
  float xt[16]; recon_read(buf[wid], coef[wid], xt);  // XT[:,j]
#pragma unroll
  for (int i = 0; i < 16; ++i) atomicAdd(&accum[(h * 16 + i) * 33 + j], xt[i]);
  __syncthreads();

  float* xp = ws + OFF_XTPART + ((size_t)(bg * CC + c) << 10);
  for (int f = tid; f < 1024; f += 256) xp[f] = accum[(f >> 5) * 33 + (f & 31)];
  if (tid == 0) ws[OFF_SSQPART + bg * CC + c] = ssqacc;
}

__global__ __launch_bounds__(256) void k3b_reduce(float* __restrict__ ws) {
  int e = blockIdx.x * 256 + threadIdx.x;  // C*1024
  int c = e >> 10, ei = e & 1023;
  float acc = 0.f;
  for (int bg = 0; bg < 64; ++bg)
    acc += ws[OFF_XTPART + ((size_t)(bg * CC + c) << 10) + ei];
  ws[OFF_GT + e] = acc * (1.f / BB);
  if (ei == 0) {
    float s = 0.f;
    for (int bg = 0; bg < 64; ++bg) s += ws[OFF_SSQPART + bg * CC + c];
    ws[OFF_SSQM + c] = s * (1.f / BB);
  }
}

__global__ __launch_bounds__(64) void k4_gt(const float* __restrict__ std_in, float* __restrict__ ws) {
  __shared__ float Gc[32 * LSTR];
  __shared__ float coefA[32];
  __shared__ float B1[32 * LSTR];   // bm^{1/2}
  __shared__ float Eb[32 * LSTR];   // expm(GT) row-major
  int c = blockIdx.x, lane = threadIdx.x & 63, j = lane & 31, h = lane >> 5;
  load_mat_lds64(ws + OFF_BMSQ + c * 1024, B1);
  float g[16];
  load_cols_global(ws + OFF_GT + c * 1024, g);
  float fr = 0.f;
#pragma unroll
  for (int i = 0; i < 16; ++i) fr = fmaf(g[i], g[i], fr);
  fr += __shfl_xor(fr, 32);
#pragma unroll
  for (int m = 1; m < 32; m <<= 1) fr += __shfl_xor(fr, m);
  float fro2 = fr;                                // ||GT||_F^2
  float sigma = 1.5f * sqrtf(fro2) + 1e-9f;       // SPD shift (GT indefinite)
#pragma unroll
  for (int i = 0; i < 16; ++i)                    // diag += sigma (no runtime reg idx)
    g[i] += (((j >> 4) == h) && ((j & 15) == i)) ? sigma : 0.f;
  jacobi(g);
  float l2 = colnorm2(g), ls = sqrtf(l2);
  float lam = ls - sigma;                         // true GT eigenvalue (signed)
  float cf = expf(lam) / fmaxf(l2, 1e-30f);
  recon_write(Gc, g);
  if (h == 0) coefA[j] = cf;
  __syncthreads();
  float e16[16]; recon_read(Gc, coefA, e16);      // E = expm(GT)
#pragma unroll
  for (int i = 0; i < 16; ++i) Eb[(h * 16 + i) * LSTR + j] = e16[i];
  __syncthreads();
  float u[32];
  { const float4* row = (const float4*)(B1 + j * LSTR);
#pragma unroll
    for (int q = 0; q < 8; ++q) { float4 r = row[q];
      u[4*q]=r.x; u[4*q+1]=r.y; u[4*q+2]=r.z; u[4*q+3]=r.w; } }
  float v[16];  matvec(Eb, u, v);
  float vf[32]; fullvec(v, vf);
  float bn[16]; matvec(B1, vf, bn);               // bm_new = bmsq E bmsq
  float* outp = ws + OFF_BMNEW + c * 1024;
#pragma unroll
  for (int i = 0; i < 16; ++i) outp[(h * 16 + i) * 32 + j] = bn[i];
  // batch_var = mean||XT||^2 - ||GT||^2 ; s = std / sqrt(var + eps)
  float var = ws[OFF_SSQM + c] - fro2;
  float s = std_in[c] / sqrtf(var + 1e-5f);
  if (threadIdx.x == 0) ws[OFF_S + c] = s;
}

__global__ __launch_bounds__(64) void k5_rm(const float* __restrict__ tparam, float* __restrict__ ws) {
  __shared__ float Gc[32 * LSTR];
  __shared__ float coefA[32], coefB[32];
  int c = blockIdx.x, lane = threadIdx.x & 63, j = lane & 31, h = lane >> 5;
  float t = tparam[0];
  float g[16];
  load_cols_global(ws + OFF_BMNEW + c * 1024, g);
  jacobi(g);
  float l2 = colnorm2(g), l = sqrtf(l2);
  float lh = fmaxf(l, 1e-6f);
  float inv_l2 = 1.f / fmaxf(l2, 1e-30f);
  float cA = inv_l2 / sqrtf(lh);                         // R = rm^{-1/2}
  float cB = expf(0.5f * (1.f - t) * logf(lh)) * inv_l2; // Msq = rm^{(1-t)/2}
  recon_write(Gc, g);
  if (h == 0) { coefA[j] = cA; coefB[j] = cB; }
  __syncthreads();
  float o[16];
  recon_read(Gc, coefA, o);
  float* Rp = ws + OFF_R + c * 1024;
#pragma unroll
  for (int i = 0; i < 16; ++i) Rp[(h * 16 + i) * 32 + j] = o[i];
  recon_read(Gc, coefB, o);
  float* Mp = ws + OFF_MSQ + c * 1024;
#pragma unroll
  for (int i = 0; i < 16; ++i) Mp[(h * 16 + i) * 32 + j] = o[i];
}

__global__ __launch_bounds__(256) void k6_stage2(const float* __restrict__ X, float* __restrict__ ws,
                                                 float* __restrict__ out) {
  __shared__ float Rlds[32 * LSTR];
  __shared__ float Mlds[32 * LSTR];
  __shared__ float buf[4][32 * LSTR];
  __shared__ float coef[4][32];
  int tid = threadIdx.x, wid = tid >> 6, lane = tid & 63, j = lane & 31, h = lane >> 5;
  int c = blockIdx.x % CC, bg = blockIdx.x / CC, b = bg * 4 + wid;
  { const float4* s = (const float4*)(ws + OFF_R + c * 1024); int f = tid * 4;
    *(float4*)(Rlds + (f >> 5) * LSTR + (f & 31)) = s[tid]; }
  { const float4* s = (const float4*)(ws + OFF_MSQ + c * 1024); int f = tid * 4;
    *(float4*)(Mlds + (f >> 5) * LSTR + (f & 31)) = s[tid]; }
  { const float4* s = (const float4*)(X + ((size_t)(b * CC + c) << 10));
    float* d = buf[wid];
#pragma unroll
    for (int q = 0; q < 4; ++q) {
      int idx = lane + 64 * q, f = idx * 4;
      *(float4*)(d + (f >> 5) * LSTR + (f & 31)) = s[idx];
    } }
  float sc = ws[OFF_S + c];
  __syncthreads();

  float qv[32];
  { const float4* row = (const float4*)(Rlds + j * LSTR);
#pragma unroll
    for (int q = 0; q < 8; ++q) { float4 r = row[q];
      qv[4*q]=r.x; qv[4*q+1]=r.y; qv[4*q+2]=r.z; qv[4*q+3]=r.w; } }
  float z[16];  matvec(buf[wid], qv, z);     // X * r_j
  float zf[32]; fullvec(z, zf);
  float g[16];  matvec(Rlds, zf, g);         // S2 = R X R

  jacobi(g);
  float l2 = colnorm2(g), l = sqrtf(l2);
  float lh = fmaxf(l, 1e-6f);
  float cf = expf(sc * logf(lh)) / fmaxf(l2, 1e-30f);   // lambda^s

  __syncthreads();
  recon_write(buf[wid], g);
  if (h == 0) coef[wid][j] = cf;
  __syncthreads();
  float p16[16]; recon_read(buf[wid], coef[wid], p16);  // P = S2^s, column j
  __syncthreads();
#pragma unroll
  for (int i = 0; i < 16; ++i) buf[wid][(h * 16 + i) * LSTR + j] = p16[i];  // P row-major
  __syncthreads();

  float u[32];
  { const float4* row = (const float4*)(Mlds + j * LSTR);
#pragma unroll
    for (int q = 0; q < 8; ++q) { float4 r = row[q];
      u[4*q]=r.x; u[4*q+1]=r.y; u[4*q+2]=r.z; u[4*q+3]=r.w; } }
  float v[16];  matvec(buf[wid], u, v);      // P * msq_j
  float vf[32]; fullvec(v, vf);
  float xn[16]; matvec(Mlds, vf, xn);        // Xn = Msq P Msq

  float* op = out + ((size_t)(b * CC + c) << 10);
#pragma unroll
  for (int i = 0; i < 16; ++i) op[(h * 16 + i) * 32 + j] = xn[i];
}

// ---------------- launch ----------------

extern "C" void kernel_launch(void* const* d_in, const int* in_sizes, int n_in,
                              void* d_out, int out_size, void* d_ws, size_t ws_size,
                              hipStream_t stream) {
  const float* X      = (const float*)d_in[0];
  const float* stdp   = (const float*)d_in[1];
  // d_in[2] running_mean, d_in[3] running_var: unused (ETA == 1.0 exactly)
  const float* tparam = (const float*)d_in[4];
  float* ws  = (float*)d_ws;
  float* out = (float*)d_out;

  k1_mean   <<<dim3((CC * 1024) / 256), dim3(256), 0, stream>>>(X, ws);
  k2_bm     <<<dim3(CC),               dim3(64),  0, stream>>>(ws);
  k3_stage1 <<<dim3(64 * CC),          dim3(256), 0, stream>>>(X, ws);
  k3b_reduce<<<dim3((CC * 1024) / 256), dim3(256), 0, stream>>>(ws);
  k4_gt     <<<dim3(CC),               dim3(64),  0, stream>>>(stdp, ws);
  k5_rm     <<<dim3(CC),               dim3(64),  0, stream>>>(tparam, ws);
  k6_stage2 <<<dim3(64 * CC),          dim3(256), 0, stream>>>(X, ws, out);
}